// Round 11
// baseline (255.199 us; speedup 1.0000x reference)
//
#include <hip/hip_runtime.h>

// CRF forward: B=512 chains, T=1024, L=48.
// Grid = 32 scan blocks + 512 score blocks (64 thr each).
//   scan block: 16 chains/wave via MFMA. Step: e'[m,c] = (sum_k Et[k][m]*e[k,c]) * w
//   done by 6 x mfma_f32_16x16x32_bf16 (M=48 as 3 16-row blocks, K=48 padded 64).
//   Lane-local pipeline: D layout (col=lane&15=chain, row=(lane>>4)*4+reg) feeds
//   the next step's B fragment through a self-chosen k-assignment g_q(i); the A
//   fragments are built from LDS with the same g_q, so correctness needs only
//   A/B fragment symmetry (k-order identical for A and B), not its exact form.
//   w = 2^(raw*log2e - cUse): raws prefetched 4 steps, cUse lag-2 damped
//   (0.5*log2(e[0]), validated R5-R7) via ONE ds_bpermute/step (off-path).
//   score block: parallel-over-t labels + gathers (validated R6-R9).
// Combined into out[b] via two atomicAdds after hipMemsetAsync(out, 0).

constexpr int Bb = 512;
constexpr int Tt = 1024;
constexpr int Ll = 48;
constexpr int NC = 16;          // chains per scan wave
constexpr int NSB = Bb / NC;    // 32 scan blocks

#define LOG2E_F 1.44269504088896340736f
#define LN2_F   0.69314718055994530942f

typedef short bf16x8 __attribute__((ext_vector_type(8)));
typedef float f32x4  __attribute__((ext_vector_type(4)));
typedef unsigned int u32x4 __attribute__((ext_vector_type(4)));

__device__ __forceinline__ float fexp2(float x) { return __builtin_amdgcn_exp2f(x); }
__device__ __forceinline__ float flog2(float x) { return __builtin_amdgcn_logf(x); }

// f32 -> bf16 bits, RNE (setup only)
__device__ __forceinline__ unsigned f2bf(float f) {
    unsigned x = __float_as_uint(f);
    return (x + 0x7FFFu + ((x >> 16) & 1u)) >> 16;
}
// packed f32x2 -> bf16x2 (per-step)
__device__ __forceinline__ unsigned pkbf(float lo, float hi) {
    unsigned r;
    asm("v_cvt_pk_bf16_f32 %0, %1, %2" : "=v"(r) : "v"(lo), "v"(hi));
    return r;
}

__global__ __launch_bounds__(64)
__attribute__((amdgpu_waves_per_eu(1, 1)))
void crf_fwd_kernel(const float* __restrict__ y_true,
                    const float* __restrict__ y_pred,
                    const float* __restrict__ trans,
                    float* __restrict__ out)
{
    const int lane = threadIdx.x;
    __shared__ float str[Ll * Ll];

    if (blockIdx.x >= NSB) {
        // -------- score block: chain b, parallel over t (lane j = t0+j) ----
        const int b = blockIdx.x - NSB;
        for (int i = lane; i < Ll * Ll; i += 64) str[i] = trans[i];
        __syncthreads();

        const float* __restrict__ yprow = y_pred + (size_t)b * Tt * Ll;
        const float* __restrict__ ytrow = y_true + (size_t)b * Tt * Ll;

        float ps = 0.f, ts = 0.f;
        int labLast = 0;

        for (int t0 = 0; t0 < Tt; t0 += 64) {
            const int t = t0 + lane;
            const float4* row = (const float4*)(ytrow + (size_t)t * Ll);
            int lab = 0;
            #pragma unroll
            for (int k = 0; k < 12; ++k) {
                float4 v = row[k];
                if (v.x > 0.5f) lab = 4 * k + 0;
                if (v.y > 0.5f) lab = 4 * k + 1;
                if (v.z > 0.5f) lab = 4 * k + 2;
                if (v.w > 0.5f) lab = 4 * k + 3;
            }
            ps += yprow[(size_t)t * Ll + lab];
            int labPrev = __shfl_up(lab, 1);
            if (lane == 0) labPrev = labLast;
            if (t > 0) ts += str[labPrev * Ll + lab];
            labLast = __builtin_amdgcn_readlane(lab, 63);
        }

        float acc = ps + ts;
        #pragma unroll
        for (int off = 32; off >= 1; off >>= 1) acc += __shfl_xor(acc, off);
        if (lane == 0) atomicAdd(&out[b], -acc);
        return;
    }

    // ---------------- scan block: chains 16*blk .. 16*blk+15 ---------------
    const int q  = lane >> 4;       // lane quad  (k-group / m-subrow)
    const int c  = lane & 15;       // chain (B col / D col) AND A row-in-tile
    const int c4 = 4 * c;           // bpermute byte index
    for (int i = lane; i < Ll * Ll; i += 64) str[i] = trans[i];
    __syncthreads();

    // A fragments: slot (q,i) holds Et[g_q(i)][16*beta + c], bf16.
    // g_q: i 0..3 -> 4q+i | i 4..7 -> 16+4q+(i-4) | i 8..11 -> 32+4q+(i-8) | 12..15 zero
    const int r0 = 4 * q;
#define EV(r, beta) fexp2(str[(r) * Ll + 16 * (beta) + c] * LOG2E_F)
#define MKA(beta)                                                              \
    bf16x8 A1_##beta, A2_##beta;                                               \
    { unsigned p0 = f2bf(EV(r0 + 0, beta)) | (f2bf(EV(r0 + 1, beta)) << 16);   \
      unsigned p1 = f2bf(EV(r0 + 2, beta)) | (f2bf(EV(r0 + 3, beta)) << 16);   \
      unsigned p2 = f2bf(EV(16 + r0 + 0, beta)) | (f2bf(EV(16 + r0 + 1, beta)) << 16); \
      unsigned p3 = f2bf(EV(16 + r0 + 2, beta)) | (f2bf(EV(16 + r0 + 3, beta)) << 16); \
      unsigned p4 = f2bf(EV(32 + r0 + 0, beta)) | (f2bf(EV(32 + r0 + 1, beta)) << 16); \
      unsigned p5 = f2bf(EV(32 + r0 + 2, beta)) | (f2bf(EV(32 + r0 + 3, beta)) << 16); \
      u32x4 ta = {p0, p1, p2, p3}; A1_##beta = __builtin_bit_cast(bf16x8, ta); \
      u32x4 tb = {p4, p5, 0u, 0u}; A2_##beta = __builtin_bit_cast(bf16x8, tb); }
    MKA(0) MKA(1) MKA(2)
#undef MKA
#undef EV

    const float* __restrict__ ypc = y_pred + (size_t)(NC * blockIdx.x + c) * Tt * Ll;

    // t = 0: e_0 = 2^(raw0*log2e), S = 0
    const float4* pr0 = (const float4*)ypc;
    float4 rv0 = pr0[q], rv1 = pr0[4 + q], rv2 = pr0[8 + q];
    float eu00 = fexp2(rv0.x * LOG2E_F), eu01 = fexp2(rv0.y * LOG2E_F);
    float eu02 = fexp2(rv0.z * LOG2E_F), eu03 = fexp2(rv0.w * LOG2E_F);
    float eu10 = fexp2(rv1.x * LOG2E_F), eu11 = fexp2(rv1.y * LOG2E_F);
    float eu12 = fexp2(rv1.z * LOG2E_F), eu13 = fexp2(rv1.w * LOG2E_F);
    float eu20 = fexp2(rv2.x * LOG2E_F), eu21 = fexp2(rv2.y * LOG2E_F);
    float eu22 = fexp2(rv2.z * LOG2E_F), eu23 = fexp2(rv2.w * LOG2E_F);
    float S = 0.f;
    float cUse = 0.5f * LOG2E_F * __uint_as_float(
        (unsigned)__builtin_amdgcn_ds_bpermute(c4, __float_as_uint(rv0.x)));

    // prefetch: rows t = 1..4
    float4 pf0a, pf0b, pf0c, pf1a, pf1b, pf1c, pf2a, pf2b, pf2c, pf3a, pf3b, pf3c;
#define LOADPF(J, tn) { const float4* pp = (const float4*)(ypc + (size_t)(tn) * Ll); \
        pf##J##a = pp[q]; pf##J##b = pp[4 + q]; pf##J##c = pp[8 + q]; }
    LOADPF(0, 1) LOADPF(1, 2) LOADPF(2, 3) LOADPF(3, 4)

#define STEP(J, tn)                                                            \
    do {                                                                       \
        /* pack B from e_{t-1} (lane-local, matches g_q) */                    \
        unsigned b0 = pkbf(eu00, eu01), b1 = pkbf(eu02, eu03);                 \
        unsigned b2 = pkbf(eu10, eu11), b3 = pkbf(eu12, eu13);                 \
        unsigned b4 = pkbf(eu20, eu21), b5 = pkbf(eu22, eu23);                 \
        u32x4 bu1 = {b0, b1, b2, b3}; u32x4 bu2 = {b4, b5, 0u, 0u};            \
        bf16x8 Bf1 = __builtin_bit_cast(bf16x8, bu1);                          \
        bf16x8 Bf2 = __builtin_bit_cast(bf16x8, bu2);                          \
        /* per-chain normalizer from e_{t-1}[0] (lag-2, off-path) */           \
        int bp = __builtin_amdgcn_ds_bpermute(c4, __float_as_uint(eu00));      \
        /* w-factors from prefetched raw + cUse (off-path) */                  \
        float u00 = fexp2(fmaf(pf##J##a.x, LOG2E_F, -cUse));                   \
        float u01 = fexp2(fmaf(pf##J##a.y, LOG2E_F, -cUse));                   \
        float u02 = fexp2(fmaf(pf##J##a.z, LOG2E_F, -cUse));                   \
        float u03 = fexp2(fmaf(pf##J##a.w, LOG2E_F, -cUse));                   \
        float u10 = fexp2(fmaf(pf##J##b.x, LOG2E_F, -cUse));                   \
        float u11 = fexp2(fmaf(pf##J##b.y, LOG2E_F, -cUse));                   \
        float u12 = fexp2(fmaf(pf##J##b.z, LOG2E_F, -cUse));                   \
        float u13 = fexp2(fmaf(pf##J##b.w, LOG2E_F, -cUse));                   \
        float u20 = fexp2(fmaf(pf##J##c.x, LOG2E_F, -cUse));                   \
        float u21 = fexp2(fmaf(pf##J##c.y, LOG2E_F, -cUse));                   \
        float u22 = fexp2(fmaf(pf##J##c.z, LOG2E_F, -cUse));                   \
        float u23 = fexp2(fmaf(pf##J##c.w, LOG2E_F, -cUse));                   \
        float cNew = 0.5f * flog2(__uint_as_float((unsigned)bp));              \
        cNew = fminf(50.f, fmaxf(-50.f, cNew));                                \
        /* matrix step: D = Et'^ . e  (3 m-blocks x 2 k-chunks) */             \
        f32x4 zz = {0.f, 0.f, 0.f, 0.f};                                       \
        f32x4 d0 = __builtin_amdgcn_mfma_f32_16x16x32_bf16(A1_0, Bf1, zz, 0, 0, 0); \
        d0 = __builtin_amdgcn_mfma_f32_16x16x32_bf16(A2_0, Bf2, d0, 0, 0, 0);  \
        f32x4 d1 = __builtin_amdgcn_mfma_f32_16x16x32_bf16(A1_1, Bf1, zz, 0, 0, 0); \
        d1 = __builtin_amdgcn_mfma_f32_16x16x32_bf16(A2_1, Bf2, d1, 0, 0, 0);  \
        f32x4 d2 = __builtin_amdgcn_mfma_f32_16x16x32_bf16(A1_2, Bf1, zz, 0, 0, 0); \
        d2 = __builtin_amdgcn_mfma_f32_16x16x32_bf16(A2_2, Bf2, d2, 0, 0, 0);  \
        /* refill prefetch slot J */                                           \
        LOADPF(J, tn)                                                          \
        /* e_t = D * w (lane-local) */                                         \
        eu00 = d0[0] * u00; eu01 = d0[1] * u01;                                \
        eu02 = d0[2] * u02; eu03 = d0[3] * u03;                                \
        eu10 = d1[0] * u10; eu11 = d1[1] * u11;                                \
        eu12 = d1[2] * u12; eu13 = d1[3] * u13;                                \
        eu20 = d2[0] * u20; eu21 = d2[1] * u21;                                \
        eu22 = d2[2] * u22; eu23 = d2[3] * u23;                                \
        S += cUse; cUse = cNew;                                                \
    } while (0)

    // main: t = 1..1020 (255 x 4), tail t = 1021..1023
    for (int t0 = 1; t0 <= Tt - 4 - 3; t0 += 4) {
        int tn3 = t0 + 7; tn3 = tn3 < Tt ? tn3 : (Tt - 1);
        STEP(0, t0 + 4);
        STEP(1, t0 + 5);
        STEP(2, t0 + 6);
        STEP(3, tn3);
    }
    STEP(0, Tt - 1);
    STEP(1, Tt - 1);
    STEP(2, Tt - 1);
#undef STEP
#undef LOADPF

    // epilogue: per-chain sum over all 48 m (12 local + cross-quad reduce)
    float sum = ((eu00 + eu01) + (eu02 + eu03))
              + ((eu10 + eu11) + (eu12 + eu13))
              + ((eu20 + eu21) + (eu22 + eu23));
    sum += __shfl_xor(sum, 16);
    sum += __shfl_xor(sum, 32);

    float res = LN2_F * (S + flog2(sum));
    if (lane < NC) atomicAdd(&out[NC * blockIdx.x + lane], res);
}

extern "C" void kernel_launch(void* const* d_in, const int* in_sizes, int n_in,
                              void* d_out, int out_size, void* d_ws, size_t ws_size,
                              hipStream_t stream) {
    const float* y_true = (const float*)d_in[0];
    const float* y_pred = (const float*)d_in[1];
    const float* trans  = (const float*)d_in[2];
    float* out = (float*)d_out;

    hipMemsetAsync(d_out, 0, (size_t)out_size * sizeof(float), stream);
    crf_fwd_kernel<<<NSB + Bb, 64, 0, stream>>>(y_true, y_pred, trans, out);
}

// Round 12
// 228.069 us; speedup vs baseline: 1.1190x; 1.1190x over previous
//
#include <hip/hip_runtime.h>

// CRF forward: B=512 chains, T=1024, L=48.
// Grid = 32 scan blocks + 512 score blocks, 128 threads each.
// Scan block = producer wave (global->reg->LDS ring, 8-row phases, load/write
// split across iterations) + consumer wave (R10-validated MFMA step, raws from
// LDS conflict-free pad-13 layout, 1-row register lookahead).
// Scan step: e'[m,c] = (sum_k Et[k][m] e[k,c]) * w; 6 independent
// mfma_f32_16x16x32_bf16 (3 m-blocks x 2 k-chunks, halves merged by v_add).
// Normalizer: damped lag-2 via one ds_bpermute (validated R5-R10, absmax=0).
// Score block: two waves split t in halves; one atomicAdd per block (plus the
// scan's add -> 2 commuting adds onto 0 = bitwise deterministic).

constexpr int Bb = 512;
constexpr int Tt = 1024;
constexpr int Ll = 48;
constexpr int NC = 16;              // chains per scan block
constexpr int NSB = Bb / NC;        // 32 scan blocks
constexpr int PH = 8;               // rows per phase
constexpr int NPH = 128;            // phases (last consumes 7 rows)
constexpr int PADC = 13;            // padded float4 chunks per chain-row
constexpr int TILE = NC * PADC * 16;// 3328 B per staged row

#define LOG2E_F 1.44269504088896340736f
#define LN2_F   0.69314718055994530942f

typedef short bf16x8 __attribute__((ext_vector_type(8)));
typedef float f32x4  __attribute__((ext_vector_type(4)));
typedef unsigned int u32x4 __attribute__((ext_vector_type(4)));

__device__ __forceinline__ float fexp2(float x) { return __builtin_amdgcn_exp2f(x); }
__device__ __forceinline__ float flog2(float x) { return __builtin_amdgcn_logf(x); }

__device__ __forceinline__ unsigned f2bf(float f) {           // RNE, setup only
    unsigned x = __float_as_uint(f);
    return (x + 0x7FFFu + ((x >> 16) & 1u)) >> 16;
}
__device__ __forceinline__ unsigned pkbf(float lo, float hi) { // packed cvt
    unsigned r;
    asm("v_cvt_pk_bf16_f32 %0, %1, %2" : "=v"(r) : "v"(lo), "v"(hi));
    return r;
}

__global__ __launch_bounds__(128)
__attribute__((amdgpu_waves_per_eu(1, 1)))
void crf_fwd_kernel(const float* __restrict__ y_true,
                    const float* __restrict__ y_pred,
                    const float* __restrict__ trans,
                    float* __restrict__ out)
{
    const int tid  = threadIdx.x;
    const int wv   = tid >> 6;
    const int lane = tid & 63;

    __shared__ float str[Ll * Ll];
    __shared__ float spart[2];
    __shared__ __align__(16) unsigned char ring[2 * PH * TILE];

    if (blockIdx.x >= NSB) {
        // ---------------- score block: chain b, waves split t --------------
        const int b = blockIdx.x - NSB;
        for (int i = tid; i < Ll * Ll; i += 128) str[i] = trans[i];
        __syncthreads();

        const float* __restrict__ yprow = y_pred + (size_t)b * Tt * Ll;
        const float* __restrict__ ytrow = y_true + (size_t)b * Tt * Ll;

        float ps = 0.f, ts = 0.f;
        int labLast = 0;
        if (wv == 1) {          // seed: label at t=511 (uniform row read)
            const float4* r5 = (const float4*)(ytrow + 511 * Ll);
            int lab = 0;
            #pragma unroll
            for (int k = 0; k < 12; ++k) {
                float4 v = r5[k];
                if (v.x > 0.5f) lab = 4 * k + 0;
                if (v.y > 0.5f) lab = 4 * k + 1;
                if (v.z > 0.5f) lab = 4 * k + 2;
                if (v.w > 0.5f) lab = 4 * k + 3;
            }
            labLast = lab;
        }
        for (int k = 0; k < 8; ++k) {
            const int t = 512 * wv + 64 * k + lane;
            const float4* row = (const float4*)(ytrow + (size_t)t * Ll);
            int lab = 0;
            #pragma unroll
            for (int kk = 0; kk < 12; ++kk) {
                float4 v = row[kk];
                if (v.x > 0.5f) lab = 4 * kk + 0;
                if (v.y > 0.5f) lab = 4 * kk + 1;
                if (v.z > 0.5f) lab = 4 * kk + 2;
                if (v.w > 0.5f) lab = 4 * kk + 3;
            }
            ps += yprow[(size_t)t * Ll + lab];
            int labPrev = __shfl_up(lab, 1);
            if (lane == 0) labPrev = labLast;
            if (t > 0) ts += str[labPrev * Ll + lab];
            labLast = __builtin_amdgcn_readlane(lab, 63);
        }
        float acc = ps + ts;
        #pragma unroll
        for (int off = 32; off >= 1; off >>= 1) acc += __shfl_xor(acc, off);
        if (lane == 0) spart[wv] = acc;
        __syncthreads();
        if (tid == 0) atomicAdd(&out[b], -(spart[0] + spart[1]));
        return;
    }

    // ---------------- scan block -------------------------------------------
    const int chain0 = NC * blockIdx.x;
    for (int i = tid; i < Ll * Ll; i += 128) str[i] = trans[i];
    __syncthreads();                                            // B0

    if (wv == 1) {
        // ============ producer wave ============
#define MKMAP(K)                                                               \
        const int idx##K = lane + 64 * (K);                                    \
        const int cc##K = idx##K / 12, pp##K = idx##K % 12;                    \
        const float4* gp##K =                                                  \
            (const float4*)(y_pred + (size_t)(chain0 + cc##K) * Tt * Ll) + pp##K; \
        const int lo##K = (cc##K * PADC + pp##K) * 16;
        MKMAP(0) MKMAP(1) MKMAP(2)
#undef MKMAP

        float4 v00, v01, v02, v10, v11, v12, v20, v21, v22, v30, v31, v32,
               v40, v41, v42, v50, v51, v52, v60, v61, v62, v70, v71, v72;

#define LDROW(J, P) { int t_ = 1 + 8 * (P) + (J); if (t_ > Tt - 1) t_ = Tt - 1; \
        v##J##0 = gp0[t_ * 12]; v##J##1 = gp1[t_ * 12]; v##J##2 = gp2[t_ * 12]; }
#define LOADREGS(P) do { LDROW(0, P) LDROW(1, P) LDROW(2, P) LDROW(3, P)       \
                         LDROW(4, P) LDROW(5, P) LDROW(6, P) LDROW(7, P) } while (0)
#define WRROW(J, WB) { *(float4*)((WB) + (J) * TILE + lo0) = v##J##0;          \
        *(float4*)((WB) + (J) * TILE + lo1) = v##J##1;                         \
        *(float4*)((WB) + (J) * TILE + lo2) = v##J##2; }
#define WRITES(P) do { unsigned char* wb_ = ring + ((P) & 1) * (PH * TILE);    \
        WRROW(0, wb_) WRROW(1, wb_) WRROW(2, wb_) WRROW(3, wb_)                \
        WRROW(4, wb_) WRROW(5, wb_) WRROW(6, wb_) WRROW(7, wb_) } while (0)

        LOADREGS(0); WRITES(0);      // phase 0 staged
        LOADREGS(1);                 // phase 1 in flight
        __syncthreads();                                        // B1
        for (int ph = 0; ph < NPH; ++ph) {
            if (ph + 1 < NPH) WRITES(ph + 1);   // waits its loads (counted vmcnt)
            if (ph + 2 < NPH) LOADREGS(ph + 2); // lands during next phase
            __syncthreads();
        }
#undef WRITES
#undef WRROW
#undef LOADREGS
#undef LDROW
        return;
    }

    // ============ consumer wave ============
    const int q  = lane >> 4;        // k-quad / m-subrow
    const int c  = lane & 15;        // chain
    const int c4 = 4 * c;

    // A fragments (validated R10): slot (q,i) = Et[g_q(i)][16*beta + c]
    const int r0 = 4 * q;
#define EV(r, beta) fexp2(str[(r) * Ll + 16 * (beta) + c] * LOG2E_F)
#define MKA(beta)                                                              \
    bf16x8 A1_##beta, A2_##beta;                                               \
    { unsigned p0 = f2bf(EV(r0 + 0, beta)) | (f2bf(EV(r0 + 1, beta)) << 16);   \
      unsigned p1 = f2bf(EV(r0 + 2, beta)) | (f2bf(EV(r0 + 3, beta)) << 16);   \
      unsigned p2 = f2bf(EV(16 + r0 + 0, beta)) | (f2bf(EV(16 + r0 + 1, beta)) << 16); \
      unsigned p3 = f2bf(EV(16 + r0 + 2, beta)) | (f2bf(EV(16 + r0 + 3, beta)) << 16); \
      unsigned p4 = f2bf(EV(32 + r0 + 0, beta)) | (f2bf(EV(32 + r0 + 1, beta)) << 16); \
      unsigned p5 = f2bf(EV(32 + r0 + 2, beta)) | (f2bf(EV(32 + r0 + 3, beta)) << 16); \
      u32x4 ta = {p0, p1, p2, p3}; A1_##beta = __builtin_bit_cast(bf16x8, ta); \
      u32x4 tb = {p4, p5, 0u, 0u}; A2_##beta = __builtin_bit_cast(bf16x8, tb); }
    MKA(0) MKA(1) MKA(2)
#undef MKA
#undef EV

    const float* __restrict__ ypc = y_pred + (size_t)(chain0 + c) * Tt * Ll;
    const float4* pr0 = (const float4*)ypc;
    float4 rv0 = pr0[q], rv1 = pr0[4 + q], rv2 = pr0[8 + q];
    float eu00 = fexp2(rv0.x * LOG2E_F), eu01 = fexp2(rv0.y * LOG2E_F);
    float eu02 = fexp2(rv0.z * LOG2E_F), eu03 = fexp2(rv0.w * LOG2E_F);
    float eu10 = fexp2(rv1.x * LOG2E_F), eu11 = fexp2(rv1.y * LOG2E_F);
    float eu12 = fexp2(rv1.z * LOG2E_F), eu13 = fexp2(rv1.w * LOG2E_F);
    float eu20 = fexp2(rv2.x * LOG2E_F), eu21 = fexp2(rv2.y * LOG2E_F);
    float eu22 = fexp2(rv2.z * LOG2E_F), eu23 = fexp2(rv2.w * LOG2E_F);
    float S = 0.f;
    float cUse = 0.5f * LOG2E_F * __uint_as_float(
        (unsigned)__builtin_amdgcn_ds_bpermute(c4, __float_as_uint(rv0.x)));

    const int off0 = (c * PADC + q) * 16;
    const int off1 = off0 + 64;
    const int off2 = off0 + 128;

#define STEP(ra, rb, rc)                                                       \
    do {                                                                       \
        unsigned xb0 = pkbf(eu00, eu01), xb1 = pkbf(eu02, eu03);               \
        unsigned xb2 = pkbf(eu10, eu11), xb3 = pkbf(eu12, eu13);               \
        unsigned xb4 = pkbf(eu20, eu21), xb5 = pkbf(eu22, eu23);               \
        u32x4 ub1 = {xb0, xb1, xb2, xb3}; u32x4 ub2 = {xb4, xb5, 0u, 0u};      \
        bf16x8 Bf1 = __builtin_bit_cast(bf16x8, ub1);                          \
        bf16x8 Bf2 = __builtin_bit_cast(bf16x8, ub2);                          \
        int bp = __builtin_amdgcn_ds_bpermute(c4, __float_as_uint(eu00));      \
        float u00 = fexp2(fmaf((ra).x, LOG2E_F, -cUse));                       \
        float u01 = fexp2(fmaf((ra).y, LOG2E_F, -cUse));                       \
        float u02 = fexp2(fmaf((ra).z, LOG2E_F, -cUse));                       \
        float u03 = fexp2(fmaf((ra).w, LOG2E_F, -cUse));                       \
        float u10 = fexp2(fmaf((rb).x, LOG2E_F, -cUse));                       \
        float u11 = fexp2(fmaf((rb).y, LOG2E_F, -cUse));                       \
        float u12 = fexp2(fmaf((rb).z, LOG2E_F, -cUse));                       \
        float u13 = fexp2(fmaf((rb).w, LOG2E_F, -cUse));                       \
        float u20 = fexp2(fmaf((rc).x, LOG2E_F, -cUse));                       \
        float u21 = fexp2(fmaf((rc).y, LOG2E_F, -cUse));                       \
        float u22 = fexp2(fmaf((rc).z, LOG2E_F, -cUse));                       \
        float u23 = fexp2(fmaf((rc).w, LOG2E_F, -cUse));                       \
        float cNew = 0.5f * flog2(__uint_as_float((unsigned)bp));              \
        cNew = fminf(50.f, fmaxf(-50.f, cNew));                                \
        f32x4 zz = {0.f, 0.f, 0.f, 0.f};                                       \
        f32x4 d0 = __builtin_amdgcn_mfma_f32_16x16x32_bf16(A1_0, Bf1, zz, 0, 0, 0); \
        f32x4 g0 = __builtin_amdgcn_mfma_f32_16x16x32_bf16(A2_0, Bf2, zz, 0, 0, 0); \
        f32x4 d1 = __builtin_amdgcn_mfma_f32_16x16x32_bf16(A1_1, Bf1, zz, 0, 0, 0); \
        f32x4 g1 = __builtin_amdgcn_mfma_f32_16x16x32_bf16(A2_1, Bf2, zz, 0, 0, 0); \
        f32x4 d2 = __builtin_amdgcn_mfma_f32_16x16x32_bf16(A1_2, Bf1, zz, 0, 0, 0); \
        f32x4 g2 = __builtin_amdgcn_mfma_f32_16x16x32_bf16(A2_2, Bf2, zz, 0, 0, 0); \
        d0 += g0; d1 += g1; d2 += g2;                                          \
        eu00 = d0[0] * u00; eu01 = d0[1] * u01;                                \
        eu02 = d0[2] * u02; eu03 = d0[3] * u03;                                \
        eu10 = d1[0] * u10; eu11 = d1[1] * u11;                                \
        eu12 = d1[2] * u12; eu13 = d1[3] * u13;                                \
        eu20 = d2[0] * u20; eu21 = d2[1] * u21;                                \
        eu22 = d2[2] * u22; eu23 = d2[3] * u23;                                \
        S += cUse; cUse = cNew;                                                \
    } while (0)

    __syncthreads();                                            // B1
    for (int ph = 0; ph < NPH; ++ph) {
        const unsigned char* base = ring + (ph & 1) * (PH * TILE);
        float4 ra = *(const float4*)(base + off0);
        float4 rb = *(const float4*)(base + off1);
        float4 rc = *(const float4*)(base + off2);
        if (ph < NPH - 1) {
            #pragma unroll
            for (int j = 0; j < 8; ++j) {
                float4 na, nb, nc;
                if (j < 7) {
                    na = *(const float4*)(base + (j + 1) * TILE + off0);
                    nb = *(const float4*)(base + (j + 1) * TILE + off1);
                    nc = *(const float4*)(base + (j + 1) * TILE + off2);
                }
                STEP(ra, rb, rc);
                if (j < 7) { ra = na; rb = nb; rc = nc; }
            }
        } else {                    // last phase: 7 steps (t = 1017..1023)
            #pragma unroll
            for (int j = 0; j < 7; ++j) {
                float4 na, nb, nc;
                if (j < 6) {
                    na = *(const float4*)(base + (j + 1) * TILE + off0);
                    nb = *(const float4*)(base + (j + 1) * TILE + off1);
                    nc = *(const float4*)(base + (j + 1) * TILE + off2);
                }
                STEP(ra, rb, rc);
                if (j < 6) { ra = na; rb = nb; rc = nc; }
            }
        }
        __syncthreads();
    }
#undef STEP

    float sum = ((eu00 + eu01) + (eu02 + eu03))
              + ((eu10 + eu11) + (eu12 + eu13))
              + ((eu20 + eu21) + (eu22 + eu23));
    sum += __shfl_xor(sum, 16);
    sum += __shfl_xor(sum, 32);

    float res = LN2_F * (S + flog2(sum));
    if (lane < NC) atomicAdd(&out[chain0 + lane], res);
}

extern "C" void kernel_launch(void* const* d_in, const int* in_sizes, int n_in,
                              void* d_out, int out_size, void* d_ws, size_t ws_size,
                              hipStream_t stream) {
    const float* y_true = (const float*)d_in[0];
    const float* y_pred = (const float*)d_in[1];
    const float* trans  = (const float*)d_in[2];
    float* out = (float*)d_out;

    hipMemsetAsync(d_out, 0, (size_t)out_size * sizeof(float), stream);
    crf_fwd_kernel<<<NSB + Bb, 128, 0, stream>>>(y_true, y_pred, trans, out);
}